// Round 1
// baseline (688.019 us; speedup 1.0000x reference)
//
#include <hip/hip_runtime.h>

#define MEM_LEN 131072
#define IN_DIM 256
#define OUT_DIM 512
#define BETA 1.0f

// ws layout (floats): [0..511] = enc (log_softmax output), [512] = loss bits (uint)

__global__ __launch_bounds__(512) void k_encode(
    const float* __restrict__ x, const float* __restrict__ W,
    const float* __restrict__ b, const float* __restrict__ mean,
    const float* __restrict__ stdv, float* __restrict__ ws)
{
    __shared__ float s_new[IN_DIM];
    __shared__ float s_wred[8];
    __shared__ float s_bcast;
    const int tid = threadIdx.x;
    const int lane = tid & 63;
    const int wave = tid >> 6;

    if (tid < IN_DIM) {
        float sd = stdv[tid];
        s_new[tid] = (sd == 0.0f) ? 0.0f : (x[tid] - mean[tid]) / sd;
    }
    __syncthreads();

    // z_j for j = tid (coalesced W reads across the wave)
    float z = b[tid];
    #pragma unroll 8
    for (int k = 0; k < IN_DIM; ++k)
        z = fmaf(s_new[k], W[k * OUT_DIM + tid], z);

    // block max
    float m = z;
    #pragma unroll
    for (int off = 32; off > 0; off >>= 1)
        m = fmaxf(m, __shfl_down(m, off, 64));
    if (lane == 0) s_wred[wave] = m;
    __syncthreads();
    if (tid == 0) {
        float mm = s_wred[0];
        for (int w = 1; w < 8; ++w) mm = fmaxf(mm, s_wred[w]);
        s_bcast = mm;
    }
    __syncthreads();
    const float zmax = s_bcast;

    // block sum of exp(z - zmax)
    float e = expf(z - zmax);
    float ssum = e;
    #pragma unroll
    for (int off = 32; off > 0; off >>= 1)
        ssum += __shfl_down(ssum, off, 64);
    __syncthreads();              // everyone has read s_bcast; safe to reuse LDS
    if (lane == 0) s_wred[wave] = ssum;
    __syncthreads();
    if (tid == 0) {
        float tot = 0.0f;
        for (int w = 0; w < 8; ++w) tot += s_wred[w];
        s_bcast = logf(tot);
        ((unsigned int*)ws)[512] = 0x7F800000u;   // +inf bits: init loss slot
    }
    __syncthreads();
    const float lse = s_bcast;

    ws[tid] = z - zmax - lse;     // enc_j
}

__global__ __launch_bounds__(256) void k_dist_copy(
    const float* __restrict__ memory, const float* __restrict__ mem_data,
    float* __restrict__ out, const float* __restrict__ ws)
{
    __shared__ alignas(16) float s_enc[OUT_DIM];
    __shared__ float s_min[4];
    const int tid = threadIdx.x;
    const int lane = tid & 63;
    const int wave = tid >> 6;

    s_enc[tid] = ws[tid];
    s_enc[256 + tid] = ws[256 + tid];
    __syncthreads();

    const float4 e0 = ((const float4*)s_enc)[lane];
    const float4 e1 = ((const float4*)s_enc)[64 + lane];

    const int gwave = blockIdx.x * 4 + wave;
    const int n_waves = gridDim.x * 4;

    float wmin = INFINITY;
    float* const out_mem = out + 1;

    for (int r = gwave; r < MEM_LEN; r += n_waves) {
        const float4* src = (const float4*)(memory + (size_t)r * OUT_DIM);
        const float4 a0 = src[lane];
        const float4 a1 = src[64 + lane];

        float s = fabsf(a0.x - e0.x) + fabsf(a0.y - e0.y)
                + fabsf(a0.z - e0.z) + fabsf(a0.w - e0.w)
                + fabsf(a1.x - e1.x) + fabsf(a1.y - e1.y)
                + fabsf(a1.z - e1.z) + fabsf(a1.w - e1.w);

        // fused copy to output (dst region offset by 1 float -> scalar stores)
        float* dst = out_mem + (size_t)r * OUT_DIM;
        const int o0 = lane * 4;
        dst[o0 + 0] = a0.x; dst[o0 + 1] = a0.y; dst[o0 + 2] = a0.z; dst[o0 + 3] = a0.w;
        dst[256 + o0 + 0] = a1.x; dst[256 + o0 + 1] = a1.y;
        dst[256 + o0 + 2] = a1.z; dst[256 + o0 + 3] = a1.w;

        #pragma unroll
        for (int off = 32; off > 0; off >>= 1)
            s += __shfl_down(s, off, 64);
        if (lane == 0) wmin = fminf(wmin, s);
    }

    if (lane == 0) s_min[wave] = wmin;
    __syncthreads();
    if (tid == 0) {
        float bm = fminf(fminf(s_min[0], s_min[1]), fminf(s_min[2], s_min[3]));
        atomicMin((unsigned int*)ws + 512, __float_as_uint(bm));
    }

    // mem_data copy (grid-stride, float4 loads, scalar stores into misaligned dst)
    const size_t total4 = (size_t)MEM_LEN * IN_DIM / 4;
    const size_t stride = (size_t)gridDim.x * 256;
    float* const out_md = out + 1 + (size_t)MEM_LEN * OUT_DIM;
    const float4* src4 = (const float4*)mem_data;
    for (size_t i = (size_t)blockIdx.x * 256 + tid; i < total4; i += stride) {
        const float4 v = src4[i];
        out_md[i * 4 + 0] = v.x; out_md[i * 4 + 1] = v.y;
        out_md[i * 4 + 2] = v.z; out_md[i * 4 + 3] = v.w;
    }
}

__global__ __launch_bounds__(512) void k_finalize(
    const float* __restrict__ x, const int* __restrict__ count,
    float* __restrict__ out, const float* __restrict__ ws)
{
    const int tid = threadIdx.x;
    const float loss = __uint_as_float(((const unsigned int*)ws)[512]);
    if (tid == 0) out[0] = loss;
    if (loss <= BETA) {
        int pos = count[0] % MEM_LEN;
        if (pos < 0) pos += MEM_LEN;
        out[1 + (size_t)pos * OUT_DIM + tid] = ws[tid];
        if (tid < IN_DIM)
            out[1 + (size_t)MEM_LEN * OUT_DIM + (size_t)pos * IN_DIM + tid] = x[tid];
    }
}

extern "C" void kernel_launch(void* const* d_in, const int* in_sizes, int n_in,
                              void* d_out, int out_size, void* d_ws, size_t ws_size,
                              hipStream_t stream) {
    const float* x        = (const float*)d_in[0];
    const float* W_enc    = (const float*)d_in[1];
    const float* b_enc    = (const float*)d_in[2];
    const float* memory   = (const float*)d_in[3];
    const float* mem_data = (const float*)d_in[4];
    const float* mean     = (const float*)d_in[5];
    const float* stdv     = (const float*)d_in[6];
    const int*   count    = (const int*)d_in[7];
    float* out = (float*)d_out;
    float* ws  = (float*)d_ws;

    k_encode<<<1, 512, 0, stream>>>(x, W_enc, b_enc, mean, stdv, ws);
    k_dist_copy<<<2048, 256, 0, stream>>>(memory, mem_data, out, ws);
    k_finalize<<<1, 512, 0, stream>>>(x, count, out, ws);
}